// Round 15
// baseline (36.387 us; speedup 1.0000x reference)
//
#include <hip/hip_runtime.h>

typedef _Float16 f16x8 __attribute__((ext_vector_type(8)));
typedef _Float16 f16x4 __attribute__((ext_vector_type(4)));
typedef float f32x4 __attribute__((ext_vector_type(4)));

#define B_N 8192
#define K_N 256
#define DIM_N 1024

// ---------------- prep_w: U=f16(Dinv-1), W=f16(-2c*Dinv) in MFMA-fragment-PACKED layout ----------------
// pk f16-index: ((cg*32 + kc)*64 + g*16 + cl)*8 + j  where class k=(cg*16+cl), dim d=(kc*32+g*8+j).
// ec[k] = -0.5*(log_det + c2): softmax_k(-0.5*acc + ec) == reference resp (row-consts cancel).
__global__ __launch_bounds__(256) void prep_w(const float* __restrict__ Dm,
                                              const float* __restrict__ Cm,
                                              _Float16* __restrict__ Upk,
                                              _Float16* __restrict__ Wpk,
                                              float* __restrict__ ec) {
    const int k = blockIdx.x, t = threadIdx.x;
    const int d = t * 4;
    const float4 dv = *(const float4*)(Dm + (size_t)k * DIM_N + d);
    const float4 cv = *(const float4*)(Cm + (size_t)k * DIM_N + d);
    float dd[4] = {dv.x, dv.y, dv.z, dv.w};
    float cc[4] = {cv.x, cv.y, cv.z, cv.w};
    f16x4 uo, wo;
    float llog = 0.f, lc2 = 0.f;
#pragma unroll
    for (int i = 0; i < 4; ++i) {
        float da = fabsf(dd[i]) + 1e-4f;
        float dinv = 1.0f / da;
        llog += logf(da);
        lc2 += cc[i] * cc[i] * dinv;
        uo[i] = (_Float16)(dinv - 1.0f);
        wo[i] = (_Float16)(-2.0f * cc[i] * dinv);
    }
    const int cg = k >> 4, cl = k & 15;
    const int kc = d >> 5, g = (d >> 3) & 3, j0 = d & 7;
    const size_t off = ((size_t)(cg * 32 + kc) * 64 + g * 16 + cl) * 8 + j0;
    *(f16x4*)(Upk + off) = uo;
    *(f16x4*)(Wpk + off) = wo;
    float both = llog + lc2;
#pragma unroll
    for (int m = 1; m <= 32; m <<= 1) both += __shfl_xor(both, m, 64);
    __shared__ float sb[4];
    if ((t & 63) == 0) sb[t >> 6] = both;
    __syncthreads();
    if (t == 0) ec[k] = -0.5f * (sb[0] + sb[1] + sb[2] + sb[3]);
}

// ---------------- gmm_fused: 16 rows x 256 classes per block, grid 512 = 2 blocks/CU ----------------
// 8 waves (512 thr), wave w owns classes w*32..w*32+31 (m1 n2, 2 products, 8 MFMA/chunk-64).
// x strip (16x1024 f16, fragment-packed, 32KB) staged ONCE -> ONE barrier in the whole GEMM.
// K-loop is pure per-wave pipeline: 2 ds_read_b128 + 2-bank packed-B register stream + 8 MFMA.
// issueB for chunk c+2 AFTER the MFMAs consume bank (register WAR hazard fixed vs r14).
// VGPR ~115 <= 128 (launch_bounds 512,4) + LDS 33KB -> two INDEPENDENT blocks per CU.
__global__ __launch_bounds__(512, 4)
void gmm_fused(const float* __restrict__ x,
               const _Float16* __restrict__ Upk,
               const _Float16* __restrict__ Wpk,
               const float* __restrict__ ecg,
               float* __restrict__ out) {
    __shared__ __align__(16) char xlds[32768];  // 16 chunks x 2 frags x 1KB (lane-linear frags)
    __shared__ float red[8][16];

    const int tid = threadIdx.x;
    const int wave = tid >> 6, lane = tid & 63;
    const int l15 = lane & 15, g4 = lane >> 4;
    const int bRow = blockIdx.x * 16;

    // staging map: row sr = tid&15 (0..15), dim group sq = tid>>4 (0..31) -> dims sq*32..sq*32+31
    const int sr = tid & 15, sq = tid >> 4;
    const float* xq = x + (size_t)(bRow + sr) * DIM_N + sq * 32;
    const int wbase = (sq >> 1) * 2048 + (sq & 1) * 1024 + sr * 16;  // chunk cl=sq>>1, frag k2=sq&1

    // B packed bases: wave's class-groups cg = wave*2 + n
    const _Float16* upb = Upk + (size_t)(wave * 2) * 32 * 512 + lane * 8;
    const _Float16* wpb = Wpk + (size_t)(wave * 2) * 32 * 512 + lane * 8;

    f32x4 acc[2];
    { f32x4 z = {0.f, 0.f, 0.f, 0.f}; acc[0] = z; acc[1] = z; }

    f16x8 ub[2][2][2], wb[2][2][2];  // [bank][n][k2]

    auto issueB = [&](int bank, int c) {
#pragma unroll
        for (int n = 0; n < 2; ++n)
#pragma unroll
            for (int k2 = 0; k2 < 2; ++k2) {
                const int kc = c * 2 + k2;
                ub[bank][n][k2] = *(const f16x8*)(upb + (size_t)(n * 32 + kc) * 512);
                wb[bank][n][k2] = *(const f16x8*)(wpb + (size_t)(n * 32 + kc) * 512);
            }
    };

    // ---- prologue: B chunks 0,1 issued; stage the whole x strip; ONE barrier ----
    issueB(0, 0);
    issueB(1, 1);
    {
        float4 v[8];
#pragma unroll
        for (int h = 0; h < 8; ++h) v[h] = *(const float4*)(xq + h * 4);
#pragma unroll
        for (int hh = 0; hh < 4; ++hh) {   // kgroup hh covers dims hh*8..hh*8+7
            const float4 a = v[hh * 2], b = v[hh * 2 + 1];
            f16x8 h8 = {(_Float16)a.x, (_Float16)a.y, (_Float16)a.z, (_Float16)a.w,
                        (_Float16)b.x, (_Float16)b.y, (_Float16)b.z, (_Float16)b.w};
            *(f16x8*)(xlds + wbase + hh * 256) = h8;
        }
    }
    __syncthreads();   // only barrier in the GEMM

    // ---- K-loop: per-wave free-running pipeline over 16 chunks ----
#pragma unroll
    for (int c = 0; c < 16; ++c) {
        const int bank = c & 1;
        const char* base = xlds + c * 2048;
        f16x8 ax0 = *(const f16x8*)(base + lane * 16);          // frag k2=0
        f16x8 ax1 = *(const f16x8*)(base + 1024 + lane * 16);   // frag k2=1
        const f16x8 a20 = ax0 * ax0;
        const f16x8 a21 = ax1 * ax1;
#pragma unroll
        for (int n = 0; n < 2; ++n) {
            acc[n] = __builtin_amdgcn_mfma_f32_16x16x32_f16(a20, ub[bank][n][0], acc[n], 0, 0, 0);
            acc[n] = __builtin_amdgcn_mfma_f32_16x16x32_f16(ax0, wb[bank][n][0], acc[n], 0, 0, 0);
            acc[n] = __builtin_amdgcn_mfma_f32_16x16x32_f16(a21, ub[bank][n][1], acc[n], 0, 0, 0);
            acc[n] = __builtin_amdgcn_mfma_f32_16x16x32_f16(ax1, wb[bank][n][1], acc[n], 0, 0, 0);
        }
        if (c < 14) issueB(bank, c + 2);   // AFTER the MFMAs consumed this bank (WAR fix)
    }

    // ---- fused epilogue: e = -0.5*acc + ec[k]; weighted row softmax across 8 waves ----
    const int cls0 = wave * 32 + l15;
    const float ecv[2] = {ecg[cls0], ecg[cls0 + 16]};

    float e[2][4];
#pragma unroll
    for (int n = 0; n < 2; ++n)
#pragma unroll
        for (int j = 0; j < 4; ++j)
            e[n][j] = fmaf(-0.5f, acc[n][j], ecv[n]);

    float mx[4];
#pragma unroll
    for (int j = 0; j < 4; ++j) mx[j] = fmaxf(e[0][j], e[1][j]);
#pragma unroll
    for (int msk = 1; msk <= 8; msk <<= 1)
#pragma unroll
        for (int j = 0; j < 4; ++j)
            mx[j] = fmaxf(mx[j], __shfl_xor(mx[j], msk, 64));
    if (l15 == 0) {
#pragma unroll
        for (int j = 0; j < 4; ++j) red[wave][g4 * 4 + j] = mx[j];
    }
    __syncthreads();
    float gm[4];
#pragma unroll
    for (int j = 0; j < 4; ++j) {
        const int r = g4 * 4 + j;
        float v = red[0][r];
#pragma unroll
        for (int w = 1; w < 8; ++w) v = fmaxf(v, red[w][r]);
        gm[j] = v;
    }
    __syncthreads();

    float p2[2][4], sfs[4];
#pragma unroll
    for (int j = 0; j < 4; ++j) sfs[j] = 0.f;
#pragma unroll
    for (int n = 0; n < 2; ++n)
#pragma unroll
        for (int j = 0; j < 4; ++j) {
            p2[n][j] = __expf(e[n][j] - gm[j]);
            sfs[j] += p2[n][j];
        }
#pragma unroll
    for (int msk = 1; msk <= 8; msk <<= 1)
#pragma unroll
        for (int j = 0; j < 4; ++j) sfs[j] += __shfl_xor(sfs[j], msk, 64);
    if (l15 == 0) {
#pragma unroll
        for (int j = 0; j < 4; ++j) red[wave][g4 * 4 + j] = sfs[j];
    }
    __syncthreads();
#pragma unroll
    for (int j = 0; j < 4; ++j) {
        const int r = g4 * 4 + j;
        float t = red[0][r];
#pragma unroll
        for (int w = 1; w < 8; ++w) t += red[w][r];
        const float inv = 1.0f / t;
#pragma unroll
        for (int n = 0; n < 2; ++n)
            out[(size_t)(bRow + r) * K_N + cls0 + n * 16] = p2[n][j] * inv;
    }
}

extern "C" void kernel_launch(void* const* d_in, const int* in_sizes, int n_in,
                              void* d_out, int out_size, void* d_ws, size_t ws_size,
                              hipStream_t stream) {
    const float* x = (const float*)d_in[0];
    const float* cen = (const float*)d_in[1];
    const float* Dm = (const float*)d_in[2];
    float* out = (float*)d_out;

    char* ws = (char*)d_ws;
    _Float16* Upk = (_Float16*)(ws);                // 512 KB packed
    _Float16* Wpk = (_Float16*)(ws + 524288);       // 512 KB packed
    float* ec = (float*)(ws + 1048576);             // 1 KB

    prep_w<<<dim3(K_N), dim3(256), 0, stream>>>(Dm, cen, Upk, Wpk, ec);
    gmm_fused<<<dim3(B_N / 16), dim3(512), 0, stream>>>(x, Upk, Wpk, ec, out);
}

// Round 16
// 30.181 us; speedup vs baseline: 1.2056x; 1.2056x over previous
//
#include <hip/hip_runtime.h>

typedef _Float16 f16x8 __attribute__((ext_vector_type(8)));
typedef _Float16 f16x4 __attribute__((ext_vector_type(4)));
typedef float f32x4 __attribute__((ext_vector_type(4)));

#define B_N 8192
#define K_N 256
#define DIM_N 1024

// ---------------- prep_w: U=f16(Dinv-1), W=f16(-2c*Dinv) in MFMA-fragment-PACKED layout ----------------
// pk f16-index: ((cg*32 + kc)*64 + g*16 + cl)*8 + j  where class k=(cg*16+cl), dim d=(kc*32+g*8+j).
// A wave reading pk + (cg*32+kc)*512 + lane*8 gets exactly the B-fragment (col=lane&15, k=(lane>>4)*8+j).
// ec[k] = -0.5*(log_det + c2): softmax_k(-0.5*acc + ec) == reference resp (row-consts cancel).
__global__ __launch_bounds__(256) void prep_w(const float* __restrict__ Dm,
                                              const float* __restrict__ Cm,
                                              _Float16* __restrict__ Upk,
                                              _Float16* __restrict__ Wpk,
                                              float* __restrict__ ec) {
    const int k = blockIdx.x, t = threadIdx.x;
    const int d = t * 4;
    const float4 dv = *(const float4*)(Dm + (size_t)k * DIM_N + d);
    const float4 cv = *(const float4*)(Cm + (size_t)k * DIM_N + d);
    float dd[4] = {dv.x, dv.y, dv.z, dv.w};
    float cc[4] = {cv.x, cv.y, cv.z, cv.w};
    f16x4 uo, wo;
    float llog = 0.f, lc2 = 0.f;
#pragma unroll
    for (int i = 0; i < 4; ++i) {
        float da = fabsf(dd[i]) + 1e-4f;
        float dinv = 1.0f / da;
        llog += logf(da);
        lc2 += cc[i] * cc[i] * dinv;
        uo[i] = (_Float16)(dinv - 1.0f);
        wo[i] = (_Float16)(-2.0f * cc[i] * dinv);
    }
    const int cg = k >> 4, cl = k & 15;
    const int kc = d >> 5, g = (d >> 3) & 3, j0 = d & 7;
    const size_t off = ((size_t)(cg * 32 + kc) * 64 + g * 16 + cl) * 8 + j0;
    *(f16x4*)(Upk + off) = uo;
    *(f16x4*)(Wpk + off) = wo;
    float both = llog + lc2;
#pragma unroll
    for (int m = 1; m <= 32; m <<= 1) both += __shfl_xor(both, m, 64);
    __shared__ float sb[4];
    if ((t & 63) == 0) sb[t >> 6] = both;
    __syncthreads();
    if (t == 0) ec[k] = -0.5f * (sb[0] + sb[1] + sb[2] + sb[3]);
}

// ---------------- gmm_fused: 32 rows x 256 classes; x staged ONCE (4 quarters), 4 barriers total ----------------
// 8 waves (512 thr), wave w owns classes w*32..w*32+31 (wave-tile 32x32, m2n2, 2 products).
// x f16 lives in 64KB LDS for the whole kernel (quarter q = chunks 4q..4q+3, never overwritten).
// x^2 fragments computed in-register from x fragments (v_pk_mul_f16) -> halves LDS traffic.
// B (U,W): register fragments from packed arrays (L2-resident), 2 banks, issued ~2 chunks ahead;
// global loads stay in flight across the 4 quarter barriers (only lgkmcnt is drained).
__global__ __launch_bounds__(512, 1)
void gmm_fused(const float* __restrict__ x,
               const _Float16* __restrict__ Upk,
               const _Float16* __restrict__ Wpk,
               const float* __restrict__ ecg,
               float* __restrict__ out) {
    __shared__ __align__(16) char xlds[65536];  // 4 quarters x [32 rows][256 dims] f16, XOR-swizzled
    __shared__ float red[8][32];

    const int tid = threadIdx.x;
    const int wave = tid >> 6, lane = tid & 63;
    const int l15 = lane & 15, g4 = lane >> 4;
    const int bRow = blockIdx.x * 32;

    // staging: thread -> row = tid>>4 (0..31); dims sd + 64*j (j=0..3) within a 256-dim quarter
    const int srow = tid >> 4, sd = (tid & 15) * 4;
    const float* xq = x + (size_t)(bRow + srow) * DIM_N + sd;
    int wB[4];
#pragma unroll
    for (int j = 0; j < 4; ++j) {
        const int slot = (sd >> 3) + 8 * j;
        wB[j] = srow * 512 + (((slot ^ (srow & 7)) << 4) | ((sd & 4) << 1));
    }

    // B packed bases: wave's class-groups cg = wave*2 + n
    const _Float16* upb = Upk + (size_t)(wave * 2) * 32 * 512 + lane * 8;
    const _Float16* wpb = Wpk + (size_t)(wave * 2) * 32 * 512 + lane * 8;

    f32x4 acc[2][2];
#pragma unroll
    for (int m = 0; m < 2; ++m)
#pragma unroll
        for (int n = 0; n < 2; ++n) { f32x4 z = {0.f, 0.f, 0.f, 0.f}; acc[m][n] = z; }

    float4 xs[2][2];           // staging regs, 2 quarter-banks
    f16x8 ub[2][2], wb[2][2];  // flattened below via issueB banks

    f16x8 ub2[2][2][2], wb2[2][2][2];  // [bank][n][k2]

    auto issueQ = [&](int bank, int q) {
        xs[bank][0] = *(const float4*)(xq + q * 256);
        xs[bank][1] = *(const float4*)(xq + q * 256 + 4);
    };
    (void)ub; (void)wb;
    auto writeQ = [&](int bank, int q) {
        // note: this kernel stages 4 dims per thread per quarter-write pair (two 8B halves)
        const float4 a = xs[bank][0];
        const float4 b = xs[bank][1];
        f16x4 h0 = {(_Float16)a.x, (_Float16)a.y, (_Float16)a.z, (_Float16)a.w};
        f16x4 h1 = {(_Float16)b.x, (_Float16)b.y, (_Float16)b.z, (_Float16)b.w};
        *(f16x4*)(xlds + q * 16384 + wB[0]) = h0;
        *(f16x4*)(xlds + q * 16384 + wB[0] + 8) = h1;
    };
    (void)writeQ;

    // ---- r9 exact staging: 4 float4 per quarter (16 dims/thread? no: 4 dims x 4 j-groups) ----
    float4 xr[2][4];
    auto issueQ4 = [&](int bank, int q) {
#pragma unroll
        for (int j = 0; j < 4; ++j) xr[bank][j] = *(const float4*)(xq + q * 256 + j * 64);
    };
    auto writeQ4 = [&](int bank, int q) {
        char* base = xlds + q * 16384;
#pragma unroll
        for (int j = 0; j < 4; ++j) {
            const float4 v = xr[bank][j];
            f16x4 h = {(_Float16)v.x, (_Float16)v.y, (_Float16)v.z, (_Float16)v.w};
            *(f16x4*)(base + wB[j]) = h;
        }
    };
    auto issueB = [&](int bank, int c) {
#pragma unroll
        for (int n = 0; n < 2; ++n)
#pragma unroll
            for (int k2 = 0; k2 < 2; ++k2) {
                const int kc = c * 2 + k2;
                ub2[bank][n][k2] = *(const f16x8*)(upb + (size_t)(n * 32 + kc) * 512);
                wb2[bank][n][k2] = *(const f16x8*)(wpb + (size_t)(n * 32 + kc) * 512);
            }
    };
    auto compute = [&](int c, int bank) {
        const char* base = xlds + (c >> 2) * 16384;
        const int cl = c & 3;
        f16x8 axf[2][2];
#pragma unroll
        for (int m = 0; m < 2; ++m)
#pragma unroll
            for (int k2 = 0; k2 < 2; ++k2) {
                const int row = m * 16 + l15;
                const int slot = cl * 8 + k2 * 4 + g4;
                axf[m][k2] = *(const f16x8*)(base + row * 512 + ((slot ^ (l15 & 7)) << 4));
            }
        __builtin_amdgcn_s_setprio(1);
#pragma unroll
        for (int m = 0; m < 2; ++m)
#pragma unroll
            for (int k2 = 0; k2 < 2; ++k2) {
                const f16x8 a2 = axf[m][k2] * axf[m][k2];   // x^2 in-register (v_pk_mul_f16)
#pragma unroll
                for (int n = 0; n < 2; ++n) {
                    acc[m][n] = __builtin_amdgcn_mfma_f32_16x16x32_f16(a2, ub2[bank][n][k2], acc[m][n], 0, 0, 0);
                    acc[m][n] = __builtin_amdgcn_mfma_f32_16x16x32_f16(axf[m][k2], wb2[bank][n][k2], acc[m][n], 0, 0, 0);
                }
            }
        __builtin_amdgcn_s_setprio(0);
    };

    // ---- staging pipeline + K-loop: 4 barriers total ----
    issueB(0, 0); issueB(1, 1);
    issueQ4(0, 0); issueQ4(1, 1);
    writeQ4(0, 0);
    issueQ4(0, 2);
    asm volatile("s_waitcnt lgkmcnt(0)" ::: "memory");
    __builtin_amdgcn_s_barrier();              // quarter 0 ready
    __builtin_amdgcn_sched_barrier(0);
    writeQ4(1, 1);
    issueQ4(1, 3);
    compute(0, 0); issueB(0, 2);
    compute(1, 1); issueB(1, 3);
    compute(2, 0); issueB(0, 4);
    compute(3, 1); issueB(1, 5);
    asm volatile("s_waitcnt lgkmcnt(0)" ::: "memory");
    __builtin_amdgcn_s_barrier();              // quarter 1 ready
    __builtin_amdgcn_sched_barrier(0);
    writeQ4(0, 2);
    compute(4, 0); issueB(0, 6);
    compute(5, 1); issueB(1, 7);
    compute(6, 0); issueB(0, 8);
    compute(7, 1); issueB(1, 9);
    asm volatile("s_waitcnt lgkmcnt(0)" ::: "memory");
    __builtin_amdgcn_s_barrier();              // quarter 2 ready
    __builtin_amdgcn_sched_barrier(0);
    writeQ4(1, 3);
    compute(8, 0);  issueB(0, 10);
    compute(9, 1);  issueB(1, 11);
    compute(10, 0); issueB(0, 12);
    compute(11, 1); issueB(1, 13);
    asm volatile("s_waitcnt lgkmcnt(0)" ::: "memory");
    __builtin_amdgcn_s_barrier();              // quarter 3 ready
    __builtin_amdgcn_sched_barrier(0);
    compute(12, 0); issueB(0, 14);
    compute(13, 1); issueB(1, 15);
    compute(14, 0);
    compute(15, 1);

    // ---- fused epilogue: e = -0.5*acc + ec[k]; weighted row softmax across waves ----
    const int cls0 = wave * 32 + l15;
    const float ecv[2] = {ecg[cls0], ecg[cls0 + 16]};

    float e[2][2][4];
#pragma unroll
    for (int m = 0; m < 2; ++m)
#pragma unroll
        for (int n = 0; n < 2; ++n)
#pragma unroll
            for (int j = 0; j < 4; ++j)
                e[m][n][j] = fmaf(-0.5f, acc[m][n][j], ecv[n]);

    float mx[2][4];
#pragma unroll
    for (int m = 0; m < 2; ++m)
#pragma unroll
        for (int j = 0; j < 4; ++j) mx[m][j] = fmaxf(e[m][0][j], e[m][1][j]);
#pragma unroll
    for (int msk = 1; msk <= 8; msk <<= 1)
#pragma unroll
        for (int m = 0; m < 2; ++m)
#pragma unroll
            for (int j = 0; j < 4; ++j)
                mx[m][j] = fmaxf(mx[m][j], __shfl_xor(mx[m][j], msk, 64));
    if (l15 == 0) {
#pragma unroll
        for (int m = 0; m < 2; ++m)
#pragma unroll
            for (int j = 0; j < 4; ++j) red[wave][m * 16 + g4 * 4 + j] = mx[m][j];
    }
    __syncthreads();
    float gm[2][4];
#pragma unroll
    for (int m = 0; m < 2; ++m)
#pragma unroll
        for (int j = 0; j < 4; ++j) {
            const int r = m * 16 + g4 * 4 + j;
            float v = red[0][r];
#pragma unroll
            for (int w = 1; w < 8; ++w) v = fmaxf(v, red[w][r]);
            gm[m][j] = v;
        }
    __syncthreads();

    float p2[2][2][4], sfs[2][4];
#pragma unroll
    for (int m = 0; m < 2; ++m)
#pragma unroll
        for (int j = 0; j < 4; ++j) sfs[m][j] = 0.f;
#pragma unroll
    for (int m = 0; m < 2; ++m)
#pragma unroll
        for (int n = 0; n < 2; ++n)
#pragma unroll
            for (int j = 0; j < 4; ++j) {
                p2[m][n][j] = __expf(e[m][n][j] - gm[m][j]);
                sfs[m][j] += p2[m][n][j];
            }
#pragma unroll
    for (int msk = 1; msk <= 8; msk <<= 1)
#pragma unroll
        for (int m = 0; m < 2; ++m)
#pragma unroll
            for (int j = 0; j < 4; ++j) sfs[m][j] += __shfl_xor(sfs[m][j], msk, 64);
    if (l15 == 0) {
#pragma unroll
        for (int m = 0; m < 2; ++m)
#pragma unroll
            for (int j = 0; j < 4; ++j) red[wave][m * 16 + g4 * 4 + j] = sfs[m][j];
    }
    __syncthreads();
#pragma unroll
    for (int m = 0; m < 2; ++m)
#pragma unroll
        for (int j = 0; j < 4; ++j) {
            const int r = m * 16 + g4 * 4 + j;
            float t = red[0][r];
#pragma unroll
            for (int w = 1; w < 8; ++w) t += red[w][r];
            const float inv = 1.0f / t;
#pragma unroll
            for (int n = 0; n < 2; ++n)
                out[(size_t)(bRow + r) * K_N + cls0 + n * 16] = p2[m][n][j] * inv;
        }
}

extern "C" void kernel_launch(void* const* d_in, const int* in_sizes, int n_in,
                              void* d_out, int out_size, void* d_ws, size_t ws_size,
                              hipStream_t stream) {
    const float* x = (const float*)d_in[0];
    const float* cen = (const float*)d_in[1];
    const float* Dm = (const float*)d_in[2];
    float* out = (float*)d_out;

    char* ws = (char*)d_ws;
    _Float16* Upk = (_Float16*)(ws);                // 512 KB packed
    _Float16* Wpk = (_Float16*)(ws + 524288);       // 512 KB packed
    float* ec = (float*)(ws + 1048576);             // 1 KB

    prep_w<<<dim3(K_N), dim3(256), 0, stream>>>(Dm, cen, Upk, Wpk, ec);
    gmm_fused<<<dim3(B_N / 32), dim3(512), 0, stream>>>(x, Upk, Wpk, ec, out);
}